// Round 1
// baseline (317.434 us; speedup 1.0000x reference)
//
#include <hip/hip_runtime.h>

typedef __bf16 bf16_t;
typedef __bf16 bf16x4 __attribute__((ext_vector_type(4)));
typedef __bf16 bf16x8 __attribute__((ext_vector_type(8)));
typedef float f32x4 __attribute__((ext_vector_type(4)));

#define D_DIM 256

// Kernel 1: row L2-normalize img and txt (fp32 -> bf16), and zero the output
// accumulator (d_out is poisoned 0xAA before every call).
// One wave per row; lane loads float4 (4 elems), wave shuffle-reduce sum-sq.
__global__ __launch_bounds__(256) void norm_cast_kernel(
    const float* __restrict__ img, const float* __restrict__ txt,
    bf16_t* __restrict__ Ab, bf16_t* __restrict__ Bb,
    float* __restrict__ out, int N)
{
    int wave = threadIdx.x >> 6;
    int lane = threadIdx.x & 63;
    int row  = blockIdx.x * 4 + wave;      // 0 .. 2N-1 (img rows then txt rows)

    const float* src;
    bf16_t* dst;
    if (row < N) {
        src = img + (size_t)row * D_DIM;
        dst = Ab  + (size_t)row * D_DIM;
    } else {
        src = txt + (size_t)(row - N) * D_DIM;
        dst = Bb  + (size_t)(row - N) * D_DIM;
    }

    float4 v = ((const float4*)src)[lane];
    float ss = v.x * v.x + v.y * v.y + v.z * v.z + v.w * v.w;
#pragma unroll
    for (int off = 32; off > 0; off >>= 1)
        ss += __shfl_xor(ss, off, 64);

    float inv = 1.0f / fmaxf(sqrtf(ss), 1e-12f);   // F.normalize eps

    bf16x4 o;
    o[0] = (bf16_t)(v.x * inv);
    o[1] = (bf16_t)(v.y * inv);
    o[2] = (bf16_t)(v.z * inv);
    o[3] = (bf16_t)(v.w * inv);
    *(bf16x4*)(dst + lane * 4) = o;                // 8B store, coalesced

    if (blockIdx.x == 0 && threadIdx.x == 0) out[0] = 0.0f;
}

// Kernel 2: fused  sum(softplus(scale*A@B^T + bias)) - diag correction.
// 128x128 tile per block, 4 waves, each wave 4x4 grid of 16x16x32 bf16 MFMA.
// A (img_n) and B (txt_n) are both row-major [N][256] == B^T layout, so both
// fragments load with the same pattern: X[m=lane&15][k=quad*8+j].
__global__ __launch_bounds__(256) void siglip_loss_kernel(
    const bf16_t* __restrict__ A, const bf16_t* __restrict__ B,
    const float* __restrict__ t_prime, const float* __restrict__ bias,
    float* __restrict__ out, int N)
{
    __shared__ bf16_t As[128 * 32];   // [row][k] row-major, 64 B/row
    __shared__ bf16_t Bs[128 * 32];
    __shared__ float red[4];

    const int tid   = threadIdx.x;
    const int wave  = tid >> 6;
    const int lane  = tid & 63;
    const int m16   = lane & 15;      // m/n index within a 16x16 MFMA tile
    const int quad  = lane >> 4;      // 0..3
    const int wm    = wave >> 1;      // wave row (0..1) in 2x2 wave grid
    const int wn    = wave & 1;       // wave col

    const int rowBase = blockIdx.y * 128;   // img rows
    const int colBase = blockIdx.x * 128;   // txt rows (= logits cols)

    const bf16_t* Ag = A + (size_t)rowBase * D_DIM;
    const bf16_t* Bg = B + (size_t)colBase * D_DIM;

    // global_load_lds mapping: lane i -> LDS base + i*16B. With 64 B/row in
    // LDS, lane i covers row i/4, k-bytes (i%4)*16 (= 8 bf16 elems).
    const int ld_r = lane >> 2;        // 0..15 row within the 16-row chunk
    const int ld_c = (lane & 3) * 8;   // k-element offset

    f32x4 acc[4][4] = {};

    for (int k0 = 0; k0 < D_DIM; k0 += 32) {
#pragma unroll
        for (int l = 0; l < 2; ++l) {
            int r0 = wave * 16 + l * 64;   // wave-uniform chunk base row
            const bf16_t* gpA = Ag + (size_t)(r0 + ld_r) * D_DIM + k0 + ld_c;
            const bf16_t* gpB = Bg + (size_t)(r0 + ld_r) * D_DIM + k0 + ld_c;
            __builtin_amdgcn_global_load_lds(
                (const __attribute__((address_space(1))) unsigned int*)gpA,
                (__attribute__((address_space(3))) unsigned int*)&As[r0 * 32],
                16, 0, 0);
            __builtin_amdgcn_global_load_lds(
                (const __attribute__((address_space(1))) unsigned int*)gpB,
                (__attribute__((address_space(3))) unsigned int*)&Bs[r0 * 32],
                16, 0, 0);
        }
        __syncthreads();   // drains vmcnt (global_load_lds) + lgkmcnt

        bf16x8 av[4], bv[4];
#pragma unroll
        for (int t = 0; t < 4; ++t) {
            av[t] = *(const bf16x8*)&As[(wm * 64 + t * 16 + m16) * 32 + quad * 8];
            bv[t] = *(const bf16x8*)&Bs[(wn * 64 + t * 16 + m16) * 32 + quad * 8];
        }
#pragma unroll
        for (int i = 0; i < 4; ++i)
#pragma unroll
            for (int j = 0; j < 4; ++j)
                acc[i][j] = __builtin_amdgcn_mfma_f32_16x16x32_bf16(
                    av[i], bv[j], acc[i][j], 0, 0, 0);
        __syncthreads();   // LDS reused next iteration
    }

    // Epilogue: loss contribution. loss*N = sum_ij softplus(z_ij) - sum_i z_ii
    const float scale = __expf(t_prime[0]);
    const float b0    = bias[0];
    float local = 0.0f;
#pragma unroll
    for (int i = 0; i < 4; ++i) {
#pragma unroll
        for (int j = 0; j < 4; ++j) {
#pragma unroll
            for (int r = 0; r < 4; ++r) {
                // C/D layout (verified m89/m91): col=lane&15, row=quad*4+r
                float z  = fmaf(scale, acc[i][j][r], b0);
                float sp = fmaxf(z, 0.0f) + __logf(1.0f + __expf(-fabsf(z)));
                local += sp;
                int grow = rowBase + wm * 64 + i * 16 + quad * 4 + r;
                int gcol = colBase + wn * 64 + j * 16 + m16;
                if (grow == gcol) local -= z;   // diagonal: softplus(-z)=sp-z
            }
        }
    }

#pragma unroll
    for (int off = 32; off > 0; off >>= 1)
        local += __shfl_xor(local, off, 64);
    if (lane == 0) red[wave] = local;
    __syncthreads();
    if (tid == 0) {
        float total = (red[0] + red[1]) + (red[2] + red[3]);
        atomicAdd(out, total / (float)N);
    }
}

extern "C" void kernel_launch(void* const* d_in, const int* in_sizes, int n_in,
                              void* d_out, int out_size, void* d_ws, size_t ws_size,
                              hipStream_t stream) {
    const float* img = (const float*)d_in[0];
    const float* txt = (const float*)d_in[1];
    const float* tp  = (const float*)d_in[2];
    const float* bs  = (const float*)d_in[3];
    float* out = (float*)d_out;
    int N = in_sizes[0] / D_DIM;    // 16384

    bf16_t* Ab = (bf16_t*)d_ws;                 // N*256 bf16 = 8 MB
    bf16_t* Bb = Ab + (size_t)N * D_DIM;        // +8 MB (ws >= 16 MB)

    norm_cast_kernel<<<(2 * N) / 4, 256, 0, stream>>>(img, txt, Ab, Bb, out, N);

    dim3 grid(N / 128, N / 128);
    siglip_loss_kernel<<<grid, 256, 0, stream>>>(Ab, Bb, tp, bs, out, N);
}

// Round 2
// 303.345 us; speedup vs baseline: 1.0464x; 1.0464x over previous
//
#include <hip/hip_runtime.h>

typedef __bf16 bf16_t;
typedef __bf16 bf16x4 __attribute__((ext_vector_type(4)));
typedef __bf16 bf16x8 __attribute__((ext_vector_type(8)));
typedef float f32x4 __attribute__((ext_vector_type(4)));

#define D_DIM 256
#define LOG2E 1.4426950408889634f
#define LN2   0.6931471805599453f

// Raw single-instruction exp2/log2 (v_exp_f32 / v_log_f32) with fallbacks.
#if __has_builtin(__builtin_amdgcn_exp2f)
static __device__ __forceinline__ float exp2_fast(float x) { return __builtin_amdgcn_exp2f(x); }
#else
static __device__ __forceinline__ float exp2_fast(float x) { return __expf(x * LN2); }
#endif
#if __has_builtin(__builtin_amdgcn_logf)
static __device__ __forceinline__ float log2_fast(float x) { return __builtin_amdgcn_logf(x); }
#else
static __device__ __forceinline__ float log2_fast(float x) { return __logf(x) * LOG2E; }
#endif

// Kernel 1: row L2-normalize img and txt (fp32 -> bf16), zero the output.
__global__ __launch_bounds__(256) void norm_cast_kernel(
    const float* __restrict__ img, const float* __restrict__ txt,
    bf16_t* __restrict__ Ab, bf16_t* __restrict__ Bb,
    float* __restrict__ out, int N)
{
    int wave = threadIdx.x >> 6;
    int lane = threadIdx.x & 63;
    int row  = blockIdx.x * 4 + wave;      // 0 .. 2N-1 (img rows then txt rows)

    const float* src;
    bf16_t* dst;
    if (row < N) {
        src = img + (size_t)row * D_DIM;
        dst = Ab  + (size_t)row * D_DIM;
    } else {
        src = txt + (size_t)(row - N) * D_DIM;
        dst = Bb  + (size_t)(row - N) * D_DIM;
    }

    float4 v = ((const float4*)src)[lane];
    float ss = v.x * v.x + v.y * v.y + v.z * v.z + v.w * v.w;
#pragma unroll
    for (int off = 32; off > 0; off >>= 1)
        ss += __shfl_xor(ss, off, 64);

    float inv = 1.0f / fmaxf(sqrtf(ss), 1e-12f);   // F.normalize eps

    bf16x4 o;
    o[0] = (bf16_t)(v.x * inv);
    o[1] = (bf16_t)(v.y * inv);
    o[2] = (bf16_t)(v.z * inv);
    o[3] = (bf16_t)(v.w * inv);
    *(bf16x4*)(dst + lane * 4) = o;                // 8B store, coalesced

    if (blockIdx.x == 0 && threadIdx.x == 0) out[0] = 0.0f;
}

// Kernel 2: fused  sum(softplus(scale*A@B^T + bias)) - diag correction.
// 128x128 tile per block, 4 waves, each wave 4x4 grid of 16x16x32 bf16 MFMA.
// Epilogue in log2 domain: softplus(z)/ln2 = log2(1 + 2^(z*log2e)); the
// diagonal correction subtracts z2 = z*log2e; final sum is scaled by ln2 once.
__global__ __launch_bounds__(256) void siglip_loss_kernel(
    const bf16_t* __restrict__ A, const bf16_t* __restrict__ B,
    const float* __restrict__ t_prime, const float* __restrict__ bias,
    float* __restrict__ out, int N)
{
    __shared__ bf16_t As[128 * 32];   // [row][k] row-major, 64 B/row
    __shared__ bf16_t Bs[128 * 32];
    __shared__ float red[4];

    const int tid   = threadIdx.x;
    const int wave  = tid >> 6;
    const int lane  = tid & 63;
    const int m16   = lane & 15;      // m/n index within a 16x16 MFMA tile
    const int quad  = lane >> 4;      // 0..3
    const int wm    = wave >> 1;      // wave row (0..1) in 2x2 wave grid
    const int wn    = wave & 1;       // wave col

    const int rowBase = blockIdx.y * 128;   // img rows
    const int colBase = blockIdx.x * 128;   // txt rows (= logits cols)

    const bf16_t* Ag = A + (size_t)rowBase * D_DIM;
    const bf16_t* Bg = B + (size_t)colBase * D_DIM;

    // global_load_lds mapping: lane i -> LDS base + i*16B. With 64 B/row in
    // LDS, lane i covers row i/4, k-bytes (i%4)*16 (= 8 bf16 elems).
    const int ld_r = lane >> 2;        // 0..15 row within the 16-row chunk
    const int ld_c = (lane & 3) * 8;   // k-element offset

    f32x4 acc[4][4] = {};

    for (int k0 = 0; k0 < D_DIM; k0 += 32) {
#pragma unroll
        for (int l = 0; l < 2; ++l) {
            int r0 = wave * 16 + l * 64;   // wave-uniform chunk base row
            const bf16_t* gpA = Ag + (size_t)(r0 + ld_r) * D_DIM + k0 + ld_c;
            const bf16_t* gpB = Bg + (size_t)(r0 + ld_r) * D_DIM + k0 + ld_c;
            __builtin_amdgcn_global_load_lds(
                (const __attribute__((address_space(1))) unsigned int*)gpA,
                (__attribute__((address_space(3))) unsigned int*)&As[r0 * 32],
                16, 0, 0);
            __builtin_amdgcn_global_load_lds(
                (const __attribute__((address_space(1))) unsigned int*)gpB,
                (__attribute__((address_space(3))) unsigned int*)&Bs[r0 * 32],
                16, 0, 0);
        }
        __syncthreads();   // drains vmcnt (global_load_lds) + lgkmcnt

        bf16x8 av[4], bv[4];
#pragma unroll
        for (int t = 0; t < 4; ++t) {
            av[t] = *(const bf16x8*)&As[(wm * 64 + t * 16 + m16) * 32 + quad * 8];
            bv[t] = *(const bf16x8*)&Bs[(wn * 64 + t * 16 + m16) * 32 + quad * 8];
        }
#pragma unroll
        for (int i = 0; i < 4; ++i)
#pragma unroll
            for (int j = 0; j < 4; ++j)
                acc[i][j] = __builtin_amdgcn_mfma_f32_16x16x32_bf16(
                    av[i], bv[j], acc[i][j], 0, 0, 0);
        __syncthreads();   // LDS reused next iteration
    }

    // Epilogue. s2/b2 fold log2e into the affine map: z2 = z*log2e.
    const float s2 = __expf(t_prime[0]) * LOG2E;
    const float b2 = bias[0] * LOG2E;
    float local = 0.0f;

    if (rowBase != colBase) {
        // 16256/16384 blocks: no diagonal possible — bookkeeping-free.
#pragma unroll
        for (int i = 0; i < 4; ++i)
#pragma unroll
            for (int j = 0; j < 4; ++j)
#pragma unroll
                for (int r = 0; r < 4; ++r) {
                    float z2 = fmaf(s2, acc[i][j][r], b2);
                    local += log2_fast(1.0f + exp2_fast(z2));
                }
    } else {
        // Diagonal block: softplus(-z) = softplus(z) - z  (subtract z2 here,
        // the final *LN2 handles the scale).
#pragma unroll
        for (int i = 0; i < 4; ++i)
#pragma unroll
            for (int j = 0; j < 4; ++j)
#pragma unroll
                for (int r = 0; r < 4; ++r) {
                    // C/D layout (verified m89/m91): col=lane&15, row=quad*4+r
                    float z2 = fmaf(s2, acc[i][j][r], b2);
                    local += log2_fast(1.0f + exp2_fast(z2));
                    int grow = wm * 64 + i * 16 + quad * 4 + r;
                    int gcol = wn * 64 + j * 16 + m16;
                    if (grow == gcol) local -= z2;
                }
    }

#pragma unroll
    for (int off = 32; off > 0; off >>= 1)
        local += __shfl_xor(local, off, 64);
    if (lane == 0) red[wave] = local;
    __syncthreads();
    if (tid == 0) {
        float total = (red[0] + red[1]) + (red[2] + red[3]);
        atomicAdd(out, total * (LN2 / (float)N));
    }
}

extern "C" void kernel_launch(void* const* d_in, const int* in_sizes, int n_in,
                              void* d_out, int out_size, void* d_ws, size_t ws_size,
                              hipStream_t stream) {
    const float* img = (const float*)d_in[0];
    const float* txt = (const float*)d_in[1];
    const float* tp  = (const float*)d_in[2];
    const float* bs  = (const float*)d_in[3];
    float* out = (float*)d_out;
    int N = in_sizes[0] / D_DIM;    // 16384

    bf16_t* Ab = (bf16_t*)d_ws;                 // N*256 bf16 = 8 MB
    bf16_t* Bb = Ab + (size_t)N * D_DIM;        // +8 MB (ws >= 16 MB)

    norm_cast_kernel<<<(2 * N) / 4, 256, 0, stream>>>(img, txt, Ab, Bb, out, N);

    dim3 grid(N / 128, N / 128);
    siglip_loss_kernel<<<grid, 256, 0, stream>>>(Ab, Bb, tp, bs, out, N);
}